// Round 5
// baseline (176.125 us; speedup 1.0000x reference)
//
#include <hip/hip_runtime.h>

// GradientCurvatureAttention: fused depthwise-conv + curvature + channel-softmax + scale.
// x: [B=16, C=128, H=128, W=128] fp32, NCHW. out: same shape.
//
// Round 5: 4 pixels/thread with aligned float4 loads. 32 lanes x 4 px = full
// W row, so shuffle halos that cross the 32-lane group boundary land exactly
// on the image edge and are killed by the existing w-masks. Block (32,16)=512
// threads (8 waves) for finer CU packing; channel softmax reduced across the
// 16 channel-groups via LDS.

#define GCA_B 16
#define GCA_C 128
#define GCA_H 128
#define GCA_W 128
#define CGRP  16           // channel groups (blockDim.y)
#define CPW   (GCA_C/CGRP) // 8 channels per group

__device__ __forceinline__ float gca_score(float rp0, float rp1, float rp2,
                                           float rm0, float rm1, float rm2,
                                           float colc) {
    const float Gx  = fmaf(2.f, rm1, rm0) + rm2;             // SOBEL_X
    const float t   = rp0 + rp2;
    const float Gy  = rp0 - rp2;                             // SOBEL_Y
    const float Iyy = fmaf(-2.f, rp1, t);                    // K_YY
    const float Ixy = rm2 - rm0;                             // K_XY
    const float Ixx = fmaf(2.f, rp1, t) - 4.f * colc;        // K_XX
    const float gy2 = Gy * Gy;
    const float g2e = fmaf(Gx, Gx, fmaf(Gy, Gy, 1e-6f));
    const float r   = rsqrtf(g2e);
    const float gm  = g2e * r;                               // sqrt(g2e)
    const float m1  = Gx * Iyy;
    const float m2  = Gy * Ixy;
    const float inner = fmaf(-2.f, m2, m1);                  // Gx*Iyy - 2*Gy*Ixy
    const float num = fmaf(gy2, Ixx, Gx * inner);
    return fmaf(num, r * r * r, gm);                         // grad_mag + curvature
}

#define GCA_SCORE(A0,B0,C0, A1,B1,C1, A2,B2,C2)                      \
    gca_score(fmaf(2.f,(B0),(A0)) + (C0),                            \
              fmaf(2.f,(B1),(A1)) + (C1),                            \
              fmaf(2.f,(B2),(A2)) + (C2),                            \
              (A0) - (C0), (A1) - (C1), (A2) - (C2),                 \
              fmaf(2.f,(B1),(B0)) + (B2))

__global__ __launch_bounds__(512, 4) void gca_fused5(const float* __restrict__ x,
                                                     float* __restrict__ out) {
    const int tx = threadIdx.x;                 // 0..31 : pixel quad, w0 = 4*tx
    const int ty = threadIdx.y;                 // 0..15 : channel group

    // XCD swizzle: 2048 blocks (= B*H, h minor), 256 consecutive ids per XCD
    // so h-neighbor rows land on the same XCD's L2.
    const int id  = blockIdx.x;
    const int swz = ((id & 7) << 8) | (id >> 3);
    const int h   = swz & 127;
    const int b   = swz >> 7;

    const int w0 = tx * 4;
    const int c0 = ty * CPW;

    const int hm = (h > 0) ? h - 1 : 0;
    const int hp = (h < GCA_H - 1) ? h + 1 : GCA_H - 1;
    const float mh0 = (h > 0) ? 1.f : 0.f;
    const float mh2 = (h < GCA_H - 1) ? 1.f : 0.f;
    const float mwA = (tx > 0) ? 1.f : 0.f;    // left halo exists
    const float mwB = (tx < 31) ? 1.f : 0.f;   // right halo exists
    const float mA0 = mwA * mh0, mB0 = mwB * mh0;
    const float mA2 = mwA * mh2, mB2 = mwB * mh2;

    const size_t plane = (size_t)GCA_H * GCA_W;
    const float* base = x   + ((size_t)b * GCA_C + c0) * plane;
    float* obase      = out + ((size_t)b * GCA_C + c0) * plane;

    const int r0off = hm * GCA_W + w0;
    const int r1off = h  * GCA_W + w0;
    const int r2off = hp * GCA_W + w0;

    float4 s[CPW];                       // scores, then exp values
    float4 lmax = make_float4(-3.0e38f, -3.0e38f, -3.0e38f, -3.0e38f);

    // Pass 1: conv + curvature scores for 4 pixels x 8 channels.
    #pragma unroll
    for (int i = 0; i < CPW; ++i) {
        const float* p = base + (size_t)i * plane;
        const float4 v0 = *(const float4*)(p + r0off);
        const float4 v1 = *(const float4*)(p + r1off);
        const float4 v2 = *(const float4*)(p + r2off);
        const float L0 = __shfl_up(v0.w, 1), R0 = __shfl_down(v0.x, 1);
        const float L1 = __shfl_up(v1.w, 1), R1 = __shfl_down(v1.x, 1);
        const float L2 = __shfl_up(v2.w, 1), R2 = __shfl_down(v2.x, 1);

        // masked columns a..f per row (a = w0-1 halo, f = w0+4 halo)
        const float a0 = L0 * mA0, b0 = v0.x * mh0, cc0 = v0.y * mh0,
                    d0 = v0.z * mh0, e0 = v0.w * mh0, f0 = R0 * mB0;
        const float a1 = L1 * mwA, b1 = v1.x, cc1 = v1.y,
                    d1 = v1.z, e1 = v1.w, f1 = R1 * mwB;
        const float a2 = L2 * mA2, b2 = v2.x * mh2, cc2 = v2.y * mh2,
                    d2 = v2.z * mh2, e2 = v2.w * mh2, f2 = R2 * mB2;

        float4 sc;
        sc.x = GCA_SCORE(a0,b0,cc0,  a1,b1,cc1,  a2,b2,cc2);
        sc.y = GCA_SCORE(b0,cc0,d0,  b1,cc1,d1,  b2,cc2,d2);
        sc.z = GCA_SCORE(cc0,d0,e0,  cc1,d1,e1,  cc2,d2,e2);
        sc.w = GCA_SCORE(d0,e0,f0,   d1,e1,f1,   d2,e2,f2);
        s[i] = sc;
        lmax.x = fmaxf(lmax.x, sc.x);
        lmax.y = fmaxf(lmax.y, sc.y);
        lmax.z = fmaxf(lmax.z, sc.z);
        lmax.w = fmaxf(lmax.w, sc.w);
    }

    // Cross-wave softmax reduction (per pixel, over the 16 channel groups).
    __shared__ float4 redmax[CGRP][32];
    __shared__ float4 redsum[CGRP][32];

    redmax[ty][tx] = lmax;
    __syncthreads();
    float4 gmax = make_float4(-3.0e38f, -3.0e38f, -3.0e38f, -3.0e38f);
    #pragma unroll
    for (int g = 0; g < CGRP; ++g) {
        const float4 m = redmax[g][tx];
        gmax.x = fmaxf(gmax.x, m.x);
        gmax.y = fmaxf(gmax.y, m.y);
        gmax.z = fmaxf(gmax.z, m.z);
        gmax.w = fmaxf(gmax.w, m.w);
    }

    float4 lsum = make_float4(0.f, 0.f, 0.f, 0.f);
    #pragma unroll
    for (int i = 0; i < CPW; ++i) {
        float4 e;
        e.x = __expf(s[i].x - gmax.x);
        e.y = __expf(s[i].y - gmax.y);
        e.z = __expf(s[i].z - gmax.z);
        e.w = __expf(s[i].w - gmax.w);
        s[i] = e;
        lsum.x += e.x; lsum.y += e.y; lsum.z += e.z; lsum.w += e.w;
    }
    redsum[ty][tx] = lsum;
    __syncthreads();
    float4 tot = make_float4(0.f, 0.f, 0.f, 0.f);
    #pragma unroll
    for (int g = 0; g < CGRP; ++g) {
        const float4 sm = redsum[g][tx];
        tot.x += sm.x; tot.y += sm.y; tot.z += sm.z; tot.w += sm.w;
    }
    const float invx = 1.f / tot.x, invy = 1.f / tot.y;
    const float invz = 1.f / tot.z, invw = 1.f / tot.w;

    // Epilogue: out = (softmax + 1) * x; center row reloaded (L2-resident).
    #pragma unroll
    for (int i = 0; i < CPW; ++i) {
        const float4 xv = *(const float4*)(base + (size_t)i * plane + r1off);
        float4 o;
        o.x = fmaf(s[i].x * invx, xv.x, xv.x);
        o.y = fmaf(s[i].y * invy, xv.y, xv.y);
        o.z = fmaf(s[i].z * invz, xv.z, xv.z);
        o.w = fmaf(s[i].w * invw, xv.w, xv.w);
        *(float4*)(obase + (size_t)i * plane + r1off) = o;
    }
}

extern "C" void kernel_launch(void* const* d_in, const int* in_sizes, int n_in,
                              void* d_out, int out_size, void* d_ws, size_t ws_size,
                              hipStream_t stream) {
    (void)in_sizes; (void)n_in; (void)d_ws; (void)ws_size; (void)out_size;
    const float* x = (const float*)d_in[0];
    float* out = (float*)d_out;
    dim3 block(32, CGRP, 1);
    dim3 grid(GCA_B * GCA_H, 1, 1);   // 2048 blocks, swizzled in-kernel
    gca_fused5<<<grid, block, 0, stream>>>(x, out);
}

// Round 6
// 69.897 us; speedup vs baseline: 2.5198x; 2.5198x over previous
//
#include <hip/hip_runtime.h>

// GradientCurvatureAttention: fused depthwise-conv + curvature + channel-softmax + scale.
// x: [B=16, C=128, H=128, W=128] fp32, NCHW. out: same shape.
//
// Round 6: float4 (4 px/thread) WITHOUT the round-5 spill: no min-occupancy
// launch bound (the (512,4) clamp forced VGPR=64 and spilled s[] -> 3x write
// traffic). Separable column-sum math: colp/colm/colyy per column shared by
// the 4 pixels; each 3x3 kernel is an outer product so derivatives are 1-2
// ops per pixel. Row-edge masks are 12 branch-free pre-muls.

#define GCA_B 16
#define GCA_C 128
#define GCA_H 128
#define GCA_W 128
#define CGRP  16           // channel groups (blockDim.y)
#define CPW   (GCA_C/CGRP) // 8 channels per group

__device__ __forceinline__ float gca_score6(float cpl, float cpc, float cpr,
                                            float cml, float cmc, float cmr,
                                            float cyl, float cyc, float cyr) {
    const float Gx  = cpl - cpr;                       // [1,2,1]v x [1,0,-1]h
    const float Gy  = fmaf(2.f, cmc, cml + cmr);       // [1,0,-1]v x [1,2,1]h
    const float Ixx = fmaf(-2.f, cpc, cpl + cpr);      // [1,2,1]v x [1,-2,1]h
    const float Ixy = cmr - cml;                       // [1,0,-1]v x [-1,0,1]h
    const float Iyy = fmaf(2.f, cyc, cyl + cyr);       // [1,-2,1]v x [1,2,1]h
    const float gy2 = Gy * Gy;
    const float g2e = fmaf(Gx, Gx, gy2 + 1e-6f);
    const float r   = rsqrtf(g2e);
    const float gm  = g2e * r;                         // sqrt(g2e)
    const float t   = Gx * Iyy;
    const float p   = Gy * Ixy;
    const float inner = fmaf(-2.f, p, t);              // Gx*Iyy - 2*Gy*Ixy
    const float q   = gy2 * Ixx;
    const float num = fmaf(Gx, inner, q);
    const float r3  = (r * r) * r;
    return fmaf(num, r3, gm);                          // grad_mag + curvature
}

__global__ __launch_bounds__(512) void gca_fused6(const float* __restrict__ x,
                                                  float* __restrict__ out) {
    const int tx = threadIdx.x;                 // 0..31 : pixel quad, w0 = 4*tx
    const int ty = threadIdx.y;                 // 0..15 : channel group

    // XCD swizzle: 2048 blocks (= B*H, h minor), 256 consecutive ids per XCD.
    const int id  = blockIdx.x;
    const int swz = ((id & 7) << 8) | (id >> 3);
    const int h   = swz & 127;
    const int b   = swz >> 7;

    const int w0 = tx * 4;
    const int c0 = ty * CPW;

    const int hm = (h > 0) ? h - 1 : 0;
    const int hp = (h < GCA_H - 1) ? h + 1 : GCA_H - 1;
    const float mh0 = (h > 0) ? 1.f : 0.f;
    const float mh2 = (h < GCA_H - 1) ? 1.f : 0.f;
    const float mwA = (tx > 0) ? 1.f : 0.f;    // left halo exists
    const float mwB = (tx < 31) ? 1.f : 0.f;   // right halo exists

    const size_t plane = (size_t)GCA_H * GCA_W;
    const float* base = x   + ((size_t)b * GCA_C + c0) * plane;
    float* obase      = out + ((size_t)b * GCA_C + c0) * plane;

    const int r0off = hm * GCA_W + w0;
    const int r1off = h  * GCA_W + w0;
    const int r2off = hp * GCA_W + w0;

    float4 s[CPW];                       // scores, then exp values
    float4 lmax = make_float4(-3.0e38f, -3.0e38f, -3.0e38f, -3.0e38f);

    // Pass 1: conv + curvature scores for 4 pixels x 8 channels.
    #pragma unroll
    for (int i = 0; i < CPW; ++i) {
        const float* p = base + (size_t)i * plane;
        float4 v0 = *(const float4*)(p + r0off);
        const float4 v1 = *(const float4*)(p + r1off);
        float4 v2 = *(const float4*)(p + r2off);
        float L0 = __shfl_up(v0.w, 1), R0 = __shfl_down(v0.x, 1);
        const float L1 = __shfl_up(v1.w, 1), R1 = __shfl_down(v1.x, 1);
        float L2 = __shfl_up(v2.w, 1), R2 = __shfl_down(v2.x, 1);

        // Row-edge masks (identity for 126/128 blocks; branch-free).
        v0.x *= mh0; v0.y *= mh0; v0.z *= mh0; v0.w *= mh0; L0 *= mh0; R0 *= mh0;
        v2.x *= mh2; v2.y *= mh2; v2.z *= mh2; v2.w *= mh2; L2 *= mh2; R2 *= mh2;

        // Column sums for cols 0..5 = w0-1 .. w0+4.
        float cp0, cp1, cp2, cp3, cp4, cp5;   // vertical [1,2,1]
        float cm0, cm1, cm2, cm3, cm4, cm5;   // vertical [1,0,-1]
        float cy0, cy1, cy2, cy3, cy4, cy5;   // vertical [1,-2,1]

        cp0 = fmaf(2.f, L1, L0 + L2) * mwA;
        cm0 = (L0 - L2) * mwA;
        cy0 = fmaf(-4.f, L1 * mwA, cp0);

        cp1 = fmaf(2.f, v1.x, v0.x + v2.x); cm1 = v0.x - v2.x; cy1 = fmaf(-4.f, v1.x, cp1);
        cp2 = fmaf(2.f, v1.y, v0.y + v2.y); cm2 = v0.y - v2.y; cy2 = fmaf(-4.f, v1.y, cp2);
        cp3 = fmaf(2.f, v1.z, v0.z + v2.z); cm3 = v0.z - v2.z; cy3 = fmaf(-4.f, v1.z, cp3);
        cp4 = fmaf(2.f, v1.w, v0.w + v2.w); cm4 = v0.w - v2.w; cy4 = fmaf(-4.f, v1.w, cp4);

        cp5 = fmaf(2.f, R1, R0 + R2) * mwB;
        cm5 = (R0 - R2) * mwB;
        cy5 = fmaf(-4.f, R1 * mwB, cp5);

        float4 sc;
        sc.x = gca_score6(cp0, cp1, cp2,  cm0, cm1, cm2,  cy0, cy1, cy2);
        sc.y = gca_score6(cp1, cp2, cp3,  cm1, cm2, cm3,  cy1, cy2, cy3);
        sc.z = gca_score6(cp2, cp3, cp4,  cm2, cm3, cm4,  cy2, cy3, cy4);
        sc.w = gca_score6(cp3, cp4, cp5,  cm3, cm4, cm5,  cy3, cy4, cy5);
        s[i] = sc;
        lmax.x = fmaxf(lmax.x, sc.x);
        lmax.y = fmaxf(lmax.y, sc.y);
        lmax.z = fmaxf(lmax.z, sc.z);
        lmax.w = fmaxf(lmax.w, sc.w);
    }

    // Cross-wave softmax reduction (per pixel, over the 16 channel groups).
    __shared__ float4 redmax[CGRP][32];
    __shared__ float4 redsum[CGRP][32];

    redmax[ty][tx] = lmax;
    __syncthreads();
    float4 gmax = make_float4(-3.0e38f, -3.0e38f, -3.0e38f, -3.0e38f);
    #pragma unroll
    for (int g = 0; g < CGRP; ++g) {
        const float4 m = redmax[g][tx];
        gmax.x = fmaxf(gmax.x, m.x);
        gmax.y = fmaxf(gmax.y, m.y);
        gmax.z = fmaxf(gmax.z, m.z);
        gmax.w = fmaxf(gmax.w, m.w);
    }

    float4 lsum = make_float4(0.f, 0.f, 0.f, 0.f);
    #pragma unroll
    for (int i = 0; i < CPW; ++i) {
        float4 e;
        e.x = __expf(s[i].x - gmax.x);
        e.y = __expf(s[i].y - gmax.y);
        e.z = __expf(s[i].z - gmax.z);
        e.w = __expf(s[i].w - gmax.w);
        s[i] = e;
        lsum.x += e.x; lsum.y += e.y; lsum.z += e.z; lsum.w += e.w;
    }
    redsum[ty][tx] = lsum;
    __syncthreads();
    float4 tot = make_float4(0.f, 0.f, 0.f, 0.f);
    #pragma unroll
    for (int g = 0; g < CGRP; ++g) {
        const float4 sm = redsum[g][tx];
        tot.x += sm.x; tot.y += sm.y; tot.z += sm.z; tot.w += sm.w;
    }
    const float invx = 1.f / tot.x, invy = 1.f / tot.y;
    const float invz = 1.f / tot.z, invw = 1.f / tot.w;

    // Epilogue: out = (softmax + 1) * x; center row reloaded (L2-resident).
    #pragma unroll
    for (int i = 0; i < CPW; ++i) {
        const float4 xv = *(const float4*)(base + (size_t)i * plane + r1off);
        float4 o;
        o.x = fmaf(s[i].x * invx, xv.x, xv.x);
        o.y = fmaf(s[i].y * invy, xv.y, xv.y);
        o.z = fmaf(s[i].z * invz, xv.z, xv.z);
        o.w = fmaf(s[i].w * invw, xv.w, xv.w);
        *(float4*)(obase + (size_t)i * plane + r1off) = o;
    }
}

extern "C" void kernel_launch(void* const* d_in, const int* in_sizes, int n_in,
                              void* d_out, int out_size, void* d_ws, size_t ws_size,
                              hipStream_t stream) {
    (void)in_sizes; (void)n_in; (void)d_ws; (void)ws_size; (void)out_size;
    const float* x = (const float*)d_in[0];
    float* out = (float*)d_out;
    dim3 block(32, CGRP, 1);
    dim3 grid(GCA_B * GCA_H, 1, 1);   // 2048 blocks, swizzled in-kernel
    gca_fused6<<<grid, block, 0, stream>>>(x, out);
}

// Round 7
// 63.906 us; speedup vs baseline: 2.7560x; 1.0937x over previous
//
#include <hip/hip_runtime.h>

// GradientCurvatureAttention: fused depthwise-conv + curvature + channel-softmax + scale.
// x: [B=16, C=128, H=128, W=128] fp32, NCHW. out: same shape.
//
// Round 7: cut instruction count.
//  - CGRP=8 x CPW=16 (block (32,8)=256): softmax cross-group reduction total
//    VALU drops 4x (8 entries/thread, half the threads).
//  - Halo via shuffled COLUMN SUMS (cp/cm/cy), not raw taps: neighbor thread
//    already applied row masks, so halo costs 6 shuffles + 6 muls, no recompute.
//  - No min-occupancy launch bound (every forced bound so far spilled).

#define GCA_B 16
#define GCA_C 128
#define GCA_H 128
#define GCA_W 128
#define CGRP  8            // channel groups (blockDim.y)
#define CPW   (GCA_C/CGRP) // 16 channels per group

__device__ __forceinline__ float gca_score7(float cpl, float cpc, float cpr,
                                            float cml, float cmc, float cmr,
                                            float cyl, float cyc, float cyr) {
    const float Gx  = cpl - cpr;                       // [1,2,1]v x [1,0,-1]h
    const float Gy  = fmaf(2.f, cmc, cml + cmr);       // [1,0,-1]v x [1,2,1]h
    const float Ixx = fmaf(-2.f, cpc, cpl + cpr);      // [1,2,1]v x [1,-2,1]h
    const float Ixy = cmr - cml;                       // [1,0,-1]v x [-1,0,1]h
    const float Iyy = fmaf(2.f, cyc, cyl + cyr);       // [1,-2,1]v x [1,2,1]h
    const float gy2 = Gy * Gy;
    const float g2e = fmaf(Gx, Gx, gy2 + 1e-6f);
    const float r   = rsqrtf(g2e);
    const float gm  = g2e * r;                         // sqrt(g2e)
    const float t   = Gx * Iyy;
    const float p   = Gy * Ixy;
    const float inner = fmaf(-2.f, p, t);              // Gx*Iyy - 2*Gy*Ixy
    const float q   = gy2 * Ixx;
    const float num = fmaf(Gx, inner, q);
    const float r3  = (r * r) * r;
    return fmaf(num, r3, gm);                          // grad_mag + curvature
}

__global__ __launch_bounds__(256) void gca_fused7(const float* __restrict__ x,
                                                  float* __restrict__ out) {
    const int tx = threadIdx.x;                 // 0..31 : pixel quad, w0 = 4*tx
    const int ty = threadIdx.y;                 // 0..7  : channel group

    // XCD swizzle: 2048 blocks (= B*H, h minor), 256 consecutive ids per XCD.
    const int id  = blockIdx.x;
    const int swz = ((id & 7) << 8) | (id >> 3);
    const int h   = swz & 127;
    const int b   = swz >> 7;

    const int w0 = tx * 4;
    const int c0 = ty * CPW;

    const int hm = (h > 0) ? h - 1 : 0;
    const int hp = (h < GCA_H - 1) ? h + 1 : GCA_H - 1;
    const float mh0 = (h > 0) ? 1.f : 0.f;
    const float mh2 = (h < GCA_H - 1) ? 1.f : 0.f;
    const float mwA = (tx > 0) ? 1.f : 0.f;    // left halo exists
    const float mwB = (tx < 31) ? 1.f : 0.f;   // right halo exists

    const size_t plane = (size_t)GCA_H * GCA_W;
    const float* base = x   + ((size_t)b * GCA_C + c0) * plane;
    float* obase      = out + ((size_t)b * GCA_C + c0) * plane;

    const int r0off = hm * GCA_W + w0;
    const int r1off = h  * GCA_W + w0;
    const int r2off = hp * GCA_W + w0;

    float4 s[CPW];                       // scores, then exp values
    float4 lmax = make_float4(-3.0e38f, -3.0e38f, -3.0e38f, -3.0e38f);

    // Pass 1: conv + curvature scores for 4 pixels x 16 channels.
    #pragma unroll
    for (int i = 0; i < CPW; ++i) {
        const float* p = base + (size_t)i * plane;
        float4 v0 = *(const float4*)(p + r0off);
        const float4 v1 = *(const float4*)(p + r1off);
        float4 v2 = *(const float4*)(p + r2off);

        // Row-edge masks (identity except h=0 / h=127).
        v0.x *= mh0; v0.y *= mh0; v0.z *= mh0; v0.w *= mh0;
        v2.x *= mh2; v2.y *= mh2; v2.z *= mh2; v2.w *= mh2;

        // Own column sums for cols w0..w0+3 (A..D).
        const float cpA = fmaf(2.f, v1.x, v0.x + v2.x);
        const float cmA = v0.x - v2.x;
        const float cyA = fmaf(-4.f, v1.x, cpA);
        const float cpB = fmaf(2.f, v1.y, v0.y + v2.y);
        const float cmB = v0.y - v2.y;
        const float cyB = fmaf(-4.f, v1.y, cpB);
        const float cpC = fmaf(2.f, v1.z, v0.z + v2.z);
        const float cmC = v0.z - v2.z;
        const float cyC = fmaf(-4.f, v1.z, cpC);
        const float cpD = fmaf(2.f, v1.w, v0.w + v2.w);
        const float cmD = v0.w - v2.w;
        const float cyD = fmaf(-4.f, v1.w, cpD);

        // Halo column sums from neighbor lanes (row masks already applied by
        // the neighbor; w-edge masks kill the garbage at lane-group edges).
        const float cpL = __shfl_up(cpD, 1) * mwA;
        const float cmL = __shfl_up(cmD, 1) * mwA;
        const float cyL = __shfl_up(cyD, 1) * mwA;
        const float cpR = __shfl_down(cpA, 1) * mwB;
        const float cmR = __shfl_down(cmA, 1) * mwB;
        const float cyR = __shfl_down(cyA, 1) * mwB;

        float4 sc;
        sc.x = gca_score7(cpL, cpA, cpB,  cmL, cmA, cmB,  cyL, cyA, cyB);
        sc.y = gca_score7(cpA, cpB, cpC,  cmA, cmB, cmC,  cyA, cyB, cyC);
        sc.z = gca_score7(cpB, cpC, cpD,  cmB, cmC, cmD,  cyB, cyC, cyD);
        sc.w = gca_score7(cpC, cpD, cpR,  cmC, cmD, cmR,  cyC, cyD, cyR);
        s[i] = sc;
        lmax.x = fmaxf(lmax.x, sc.x);
        lmax.y = fmaxf(lmax.y, sc.y);
        lmax.z = fmaxf(lmax.z, sc.z);
        lmax.w = fmaxf(lmax.w, sc.w);
    }

    // Cross-group softmax reduction (per pixel, over the 8 channel groups).
    __shared__ float4 redmax[CGRP][32];
    __shared__ float4 redsum[CGRP][32];

    redmax[ty][tx] = lmax;
    __syncthreads();
    float4 gmax = make_float4(-3.0e38f, -3.0e38f, -3.0e38f, -3.0e38f);
    #pragma unroll
    for (int g = 0; g < CGRP; ++g) {
        const float4 m = redmax[g][tx];
        gmax.x = fmaxf(gmax.x, m.x);
        gmax.y = fmaxf(gmax.y, m.y);
        gmax.z = fmaxf(gmax.z, m.z);
        gmax.w = fmaxf(gmax.w, m.w);
    }

    float4 lsum = make_float4(0.f, 0.f, 0.f, 0.f);
    #pragma unroll
    for (int i = 0; i < CPW; ++i) {
        float4 e;
        e.x = __expf(s[i].x - gmax.x);
        e.y = __expf(s[i].y - gmax.y);
        e.z = __expf(s[i].z - gmax.z);
        e.w = __expf(s[i].w - gmax.w);
        s[i] = e;
        lsum.x += e.x; lsum.y += e.y; lsum.z += e.z; lsum.w += e.w;
    }
    redsum[ty][tx] = lsum;
    __syncthreads();
    float4 tot = make_float4(0.f, 0.f, 0.f, 0.f);
    #pragma unroll
    for (int g = 0; g < CGRP; ++g) {
        const float4 sm = redsum[g][tx];
        tot.x += sm.x; tot.y += sm.y; tot.z += sm.z; tot.w += sm.w;
    }
    const float invx = 1.f / tot.x, invy = 1.f / tot.y;
    const float invz = 1.f / tot.z, invw = 1.f / tot.w;

    // Epilogue: out = (softmax + 1) * x; center row reloaded (L2-resident).
    #pragma unroll
    for (int i = 0; i < CPW; ++i) {
        const float4 xv = *(const float4*)(base + (size_t)i * plane + r1off);
        float4 o;
        o.x = fmaf(s[i].x * invx, xv.x, xv.x);
        o.y = fmaf(s[i].y * invy, xv.y, xv.y);
        o.z = fmaf(s[i].z * invz, xv.z, xv.z);
        o.w = fmaf(s[i].w * invw, xv.w, xv.w);
        *(float4*)(obase + (size_t)i * plane + r1off) = o;
    }
}

extern "C" void kernel_launch(void* const* d_in, const int* in_sizes, int n_in,
                              void* d_out, int out_size, void* d_ws, size_t ws_size,
                              hipStream_t stream) {
    (void)in_sizes; (void)n_in; (void)d_ws; (void)ws_size; (void)out_size;
    const float* x = (const float*)d_in[0];
    float* out = (float*)d_out;
    dim3 block(32, CGRP, 1);
    dim3 grid(GCA_B * GCA_H, 1, 1);   // 2048 blocks, swizzled in-kernel
    gca_fused7<<<grid, block, 0, stream>>>(x, out);
}